// Round 6
// baseline (328.100 us; speedup 1.0000x reference)
//
#include <hip/hip_runtime.h>
#include <math.h>

#define C_DIM 128
#define POOL_CHUNK 64
#define BKT_SHIFT 7          // 128 nodes per destination bucket
#define MAX_B 1024           // bucket arrays capacity (B = ceil(N/128) = 782)
#define CB 256               // edge chunk blocks
#define CHUNK_MAX 6400       // per-block LDS sort capacity (chunk = 6252)
#define FB_CAP 8192          // bfinal LDS edge-staging capacity (avg bucket ~2048)
typedef unsigned short ushort_t;
typedef __attribute__((ext_vector_type(8))) short short8;
typedef __attribute__((ext_vector_type(4))) float f32x4;
typedef __attribute__((ext_vector_type(2))) float f32x2;  // -> v_pk_add_f32

static inline int ceil_div(int a, int b) { return (a + b - 1) / b; }

// bf16 round-to-nearest-even (unbiased — truncation would bias sums)
__device__ inline ushort_t f2bf(float f) {
    union { float f; unsigned u; } v; v.f = f;
    unsigned r = v.u + 0x7FFFu + ((v.u >> 16) & 1u);
    return (ushort_t)(r >> 16);
}
__device__ inline float bf_lo(unsigned u) {
    union { unsigned v; float f; } c; c.v = u << 16; return c.f;
}
__device__ inline float bf_hi(unsigned u) {
    union { unsigned v; float f; } c; c.v = u & 0xFFFF0000u; return c.f;
}
// packed accumulate: 2 unpack VALU + 1 v_pk_add_f32 per dword
__device__ inline void accum8pk(uint4 u, f32x2 ac[4]) {
    ac[0] += (f32x2){bf_lo(u.x), bf_hi(u.x)};
    ac[1] += (f32x2){bf_lo(u.y), bf_hi(u.y)};
    ac[2] += (f32x2){bf_lo(u.z), bf_hi(u.z)};
    ac[3] += (f32x2){bf_lo(u.w), bf_hi(u.w)};
}

// ============ CSR build: block-local LDS counting sort (dense writes) =======
// 512 threads/block (8 waves/CU at 1 block/CU). SINGLE global edge read.
__global__ __launch_bounds__(512) void k_sortchunk(
    const int* __restrict__ row, const int* __restrict__ col, int E, int chunk,
    int B, int* __restrict__ counts, int* __restrict__ sstart,
    int* __restrict__ epk,
    const float* __restrict__ W1, const float* __restrict__ W2,
    uint4* __restrict__ wf1, uint4* __restrict__ wf2,
    float* __restrict__ gsums, int GC, int* __restrict__ cursor) {
    int t = threadIdx.x, blk = blockIdx.x;
    if (blk >= CB) {   // weight fragment pre-pack
        const float* W = (blk == CB) ? W1 : W2;
        uint4* wf = (blk == CB) ? wf1 : wf2;
        for (int f = t; f < 2048; f += 512) {
            int lane = f & 63, kkn = f >> 6;
            int kk = kkn & 3, nt = kkn >> 2;
            int n = lane & 15, quad = lane >> 4;
            union { ushort_t h[8]; uint4 v; } u;
#pragma unroll
            for (int j = 0; j < 8; ++j)
                u.h[j] = f2bf(W[(size_t)(kk * 32 + quad * 8 + j) * C_DIM + nt * 16 + n]);
            wf[f] = u.v;
        }
        return;
    }
    // zero gsums + cursor (consumers run much later in the stream)
    for (int i = blk * 512 + t; i < GC; i += CB * 512) gsums[i] = 0.f;
    if (blk == 0 && t == 0) *cursor = 0;

    __shared__ int hist[MAX_B];                      // 4 KB
    __shared__ int hscan[MAX_B];                     // 4 KB
    __shared__ int sd[512];                          // 2 KB
    __shared__ __align__(16) int ebuf[CHUNK_MAX];    // 25.6 KB packed (r<<7)|(c&127)
    __shared__ __align__(8)  ushort_t bbuf[CHUNK_MAX]; // 12.8 KB bucket ids
    __shared__ int sorted[CHUNK_MAX];                // 25.6 KB

    for (int i = t; i < B; i += 512) hist[i] = 0;
    __syncthreads();
    int s = blk * chunk;                     // chunk % 4 == 0, E % 4 == 0
    int e = s + chunk; if (e > E) e = E;
    int cnt = e - s;                         // multiple of 4
    for (int i = s + 4 * t; i < e; i += 2048) {
        int4 c = *(const int4*)(col + i);
        int4 r = *(const int4*)(row + i);
        int li = i - s;
        int4 pk;
        pk.x = (r.x << 7) | (c.x & 127);
        pk.y = (r.y << 7) | (c.y & 127);
        pk.z = (r.z << 7) | (c.z & 127);
        pk.w = (r.w << 7) | (c.w & 127);
        *(int4*)&ebuf[li] = pk;
        ushort4 bk;
        bk.x = (ushort_t)(c.x >> BKT_SHIFT);
        bk.y = (ushort_t)(c.y >> BKT_SHIFT);
        bk.z = (ushort_t)(c.z >> BKT_SHIFT);
        bk.w = (ushort_t)(c.w >> BKT_SHIFT);
        *(ushort4*)&bbuf[li] = bk;
        atomicAdd(&hist[bk.x], 1);
        atomicAdd(&hist[bk.y], 1);
        atomicAdd(&hist[bk.z], 1);
        atomicAdd(&hist[bk.w], 1);
    }
    __syncthreads();
    // blocked exclusive scan of hist[0..B) -> hscan  (512 threads x 2 bins)
    {
        int base2 = t * 2;
        int vv[2]; int sum = 0;
#pragma unroll
        for (int j = 0; j < 2; ++j) {
            int idx = base2 + j;
            vv[j] = (idx < B) ? hist[idx] : 0;
            sum += vv[j];
        }
        sd[t] = sum;
        __syncthreads();
        for (int off = 1; off < 512; off <<= 1) {
            int x = (t >= off) ? sd[t - off] : 0;
            __syncthreads();
            sd[t] += x;
            __syncthreads();
        }
        int run = sd[t] - sum;
#pragma unroll
        for (int j = 0; j < 2; ++j) {
            int idx = base2 + j;
            if (idx < B) hscan[idx] = run;
            run += vv[j];
        }
    }
    __syncthreads();
    for (int i = t; i < B; i += 512) {
        counts[(size_t)blk * MAX_B + i] = hist[i];
        sstart[(size_t)blk * MAX_B + i] = hscan[i];
    }
    __syncthreads();
    for (int i = t; i < B; i += 512) hist[i] = hscan[i];  // reuse as cursor
    __syncthreads();
    for (int i = t; i < cnt; i += 512) {
        int pos = atomicAdd(&hist[bbuf[i]], 1);
        sorted[pos] = ebuf[i];
    }
    __syncthreads();
    for (int i = t; i * 4 < cnt; i += 512)
        *(int4*)&epk[s + i * 4] = *(const int4*)&sorted[i * 4];
}

// Final: per bucket, gather its CB segments (serial per-thread staging —
// r4-proven; the r5 cooperative variant is the prime crash suspect and is
// reverted), LDS-stage, per-node count, scan, write (start, aligned-end)+dinv,
// csr. Per-node segments padded to x4 with zero-row (N<<8) entries. Also emits
// in-bucket DEGREE-SORTED perm (r1-proven code) so the aggregate's
// 2-nodes-per-wave pairs have near-equal trip counts.
__global__ __launch_bounds__(256) void k_bfinal(
    const int* __restrict__ epk, const int* __restrict__ counts,
    const int* __restrict__ sstart, int* __restrict__ cursor,
    int chunk, int N,
    int2* __restrict__ offs2, float* __restrict__ dinv, int* __restrict__ csr,
    int* __restrict__ perm) {
    __shared__ int sh[FB_CAP];       // 32 KB
    __shared__ int sd[256];
    __shared__ int cnt[128];
    __shared__ int pre[128];
    __shared__ int cur[128];
    __shared__ int dbin[64];
    __shared__ int dsc[64];
    __shared__ int dcur[64];
    __shared__ int sbase_s;
    int bkt = blockIdx.x, t = threadIdx.x;
    int base = bkt << BKT_SHIFT;
    int nn = N - base; if (nn > 128) nn = 128;

    int segln = counts[(size_t)t * MAX_B + bkt];
    int gs = t * chunk + sstart[(size_t)t * MAX_B + bkt];
    sd[t] = segln;
    __syncthreads();
    for (int off = 1; off < 256; off <<= 1) {
        int x = (t >= off) ? sd[t - off] : 0;
        __syncthreads();
        sd[t] += x;
        __syncthreads();
    }
    int place = sd[t] - segln;
    int m = sd[255];                 // raw edge count in bucket
    if (t < 128) cnt[t] = 0;
    __syncthreads();

    bool fits = (m <= FB_CAP);
    if (fits) {
        for (int j = 0; j < segln; ++j) {
            int u = epk[gs + j];
            sh[place + j] = u;
            atomicAdd(&cnt[u & 127], 1);
        }
    } else {
        for (int j = 0; j < segln; ++j)
            atomicAdd(&cnt[epk[gs + j] & 127], 1);
    }
    __syncthreads();
    // aligned (multiple-of-4) per-node placement
    if (t < 128) pre[t] = (cnt[t] + 3) & ~3;
    __syncthreads();
    for (int off = 1; off < 128; off <<= 1) {
        int x = (t >= off && t < 128) ? pre[t - off] : 0;
        __syncthreads();
        if (t < 128) pre[t] += x;
        __syncthreads();
    }
    if (t == 127) sbase_s = atomicAdd(cursor, pre[127]);
    __syncthreads();
    int sbase = sbase_s;
    if (t < 128) {
        int c4 = (cnt[t] + 3) & ~3;
        int ex = pre[t] - c4;
        cur[t] = ex;
        if (t < nn) {
            offs2[base + t] = make_int2(sbase + ex, sbase + ex + c4);
            dinv[base + t] = 1.0f / sqrtf((float)cnt[t] + 1.0f);
        }
    }
    __syncthreads();
    if (fits) {
        for (int i = t; i < m; i += 256) {
            int u = sh[i];
            int slot = atomicAdd(&cur[u & 127], 1);
            csr[sbase + slot] = (u >> 7) << 8;      // src * 256B row pitch
        }
    } else {
        for (int j = 0; j < segln; ++j) {
            int u = epk[gs + j];
            int slot = atomicAdd(&cur[u & 127], 1);
            csr[sbase + slot] = (u >> 7) << 8;
        }
    }
    __syncthreads();
    // fill pad slots with the zero-row offset
    if (t < nn) {
        int c4 = (cnt[t] + 3) & ~3;
        int ex = pre[t] - c4;
        int zoff = N << 8;
        for (int k2 = cnt[t]; k2 < c4; ++k2) csr[sbase + ex + k2] = zoff;
    }
    // ---- in-bucket degree sort -> perm (pad slots dup last valid node) ----
    __syncthreads();
    if (t < 64) { dbin[t] = 0; dcur[t] = 0; }
    __syncthreads();
    int deg = 0, bidx = 0, tn = 0;
    if (t < 128) {
        tn = (t < nn) ? t : (nn - 1);
        deg = cnt[tn];
        bidx = deg > 63 ? 63 : deg;
        atomicAdd(&dbin[bidx], 1);
    }
    __syncthreads();
    if (t < 64) dsc[t] = dbin[t];
    __syncthreads();
    for (int off = 1; off < 64; off <<= 1) {
        int x = (t >= off && t < 64) ? dsc[t - off] : 0;
        __syncthreads();
        if (t < 64) dsc[t] += x;
        __syncthreads();
    }
    if (t < 128) {
        int rank = dsc[bidx] - dbin[bidx] + atomicAdd(&dcur[bidx], 1);
        perm[(bkt << 7) + rank] = base + tn;
    }
}

// ============ MFMA matmul [N,128]@[128,128] -> bf16 table, scaled by dinv ===
// 64-row blocks, 49.4 KB LDS -> 3 blocks/CU, 1563 blocks. Also zeroes row N
// (the aggregate's pad target).
template <int ABF16>
__global__ __launch_bounds__(256) void k_matmul_mfma(
    const float* __restrict__ Af, const ushort_t* __restrict__ Abf,
    const uint4* __restrict__ wfrag, const float* __restrict__ dinv,
    ushort_t* __restrict__ Cb, int N) {
    __shared__ uint4 wfs[2048];                       // 32 KB
    __shared__ __align__(16) ushort_t As[64 * 136];   // 17.4 KB (also epilogue)
    int t = threadIdx.x;
    int wv = t >> 6, lane = t & 63;
    int n = lane & 15, quad = lane >> 4;
    int row0 = blockIdx.x * 64;

    for (int i = t; i < 2048; i += 256) wfs[i] = wfrag[i];

    if (ABF16) {
#pragma unroll
        for (int i = 0; i < 4; ++i) {
            int idx = i * 256 + t;
            int r = idx >> 4, c8 = idx & 15;
            int grow = row0 + r; if (grow >= N) grow = N - 1;
            uint4 u = *(const uint4*)(Abf + (size_t)grow * C_DIM + c8 * 8);
            *(uint4*)&As[r * 136 + c8 * 8] = u;
        }
    } else {
#pragma unroll
        for (int i = 0; i < 8; ++i) {
            int idx = i * 256 + t;
            int r = idx >> 5, cq = idx & 31;
            int grow = row0 + r; if (grow >= N) grow = N - 1;
            float4 f = *(const float4*)(Af + (size_t)grow * C_DIM + cq * 4);
            union { ushort_t h[4]; uint2 v; } c;
            c.h[0] = f2bf(f.x); c.h[1] = f2bf(f.y);
            c.h[2] = f2bf(f.z); c.h[3] = f2bf(f.w);
            *(uint2*)&As[r * 136 + cq * 4] = c.v;
        }
    }

    f32x4 acc[8];
#pragma unroll
    for (int i = 0; i < 8; ++i) acc[i] = (f32x4){0.f, 0.f, 0.f, 0.f};

    __syncthreads();

    int rl = wv * 16 + n;
#pragma unroll
    for (int kk = 0; kk < 4; ++kk) {
        union { uint4 v; short8 s; } ca;
        ca.v = *(const uint4*)&As[rl * 136 + kk * 32 + quad * 8];
#pragma unroll
        for (int nt = 0; nt < 8; ++nt) {
            union { uint4 v; short8 s; } cb;
            cb.v = wfs[(nt * 4 + kk) * 64 + lane];
            acc[nt] = __builtin_amdgcn_mfma_f32_16x16x32_bf16(ca.s, cb.s, acc[nt], 0, 0, 0);
        }
    }

    __syncthreads();
#pragma unroll
    for (int reg = 0; reg < 4; ++reg) {
        int lr = wv * 16 + quad * 4 + reg;
        int grow = row0 + lr;
        float sc = dinv[grow < N ? grow : N - 1];
#pragma unroll
        for (int nt = 0; nt < 8; ++nt)
            As[lr * 136 + nt * 16 + n] = f2bf(acc[nt][reg] * sc);
    }
    __syncthreads();
    int rows = N - row0; if (rows > 64) rows = 64;
    for (int idx = t; idx < 16 * 64; idx += 256) {
        int r = idx >> 4, c8 = idx & 15;
        if (r < rows)
            *(uint4*)(Cb + (size_t)(row0 + r) * C_DIM + c8 * 8) =
                *(const uint4*)&As[r * 136 + c8 * 8];
        else if (row0 + r == N)   // zero row N: pad target for aggregate
            *(uint4*)(Cb + (size_t)N * C_DIM + c8 * 8) = (uint4){0, 0, 0, 0};
    }
}

// ---------------- per-node gather-reduce aggregation (bf16 in/out) -----------
// 2 nodes per wave (32 lanes each), nodes ADJACENT IN DEGREE-SORTED ORDER
// (perm) so both halves run near-equal trip counts (kills the ~25%
// predicated-issue waste from Poisson degree spread). csr segments 4-aligned
// with zero-row pads: int4 idx loads, no scalar tail. csr = byte offsets.
// Duplicate perm entries (bucket tail) recompute identical outputs — benign.
template <int RELU>
__global__ __launch_bounds__(256) void k_aggregate(
    const ushort_t* __restrict__ hs, const int2* __restrict__ offs2,
    const int* __restrict__ csr, const float* __restrict__ dinv,
    const int* __restrict__ perm, const float* __restrict__ bias,
    uint4* __restrict__ outV, int N) {
    int t = threadIdx.x & 63;
    int half = t >> 5;               // which of the wave's 2 nodes
    int q2 = (t >> 4) & 1;           // edge-slot group within the half
    int fs = t & 15;                 // 16B channel slot (8 channels)
    int bkt = blockIdx.x >> 4;       // 16 blocks per bucket (8 nodes each)
    int pos = ((blockIdx.x & 15) << 3) + ((threadIdx.x >> 6) << 1) + half;
    int node = perm[(bkt << 7) + pos];
    const char* hb = (const char*)hs;
    unsigned fso = (unsigned)(fs << 4);
    int2 se = offs2[node];
    int j = se.x, e = se.y;          // e - j is a multiple of 4 (zero-row pads)

    f32x2 ac[4];
    if (q2 == 0) {                   // self-loop
        uint4 u = *(const uint4*)(hb + ((unsigned)node << 8) + fso);
        ac[0] = (f32x2){bf_lo(u.x), bf_hi(u.x)};
        ac[1] = (f32x2){bf_lo(u.y), bf_hi(u.y)};
        ac[2] = (f32x2){bf_lo(u.z), bf_hi(u.z)};
        ac[3] = (f32x2){bf_lo(u.w), bf_hi(u.w)};
    } else {
#pragma unroll
        for (int i = 0; i < 4; ++i) ac[i] = (f32x2){0.f, 0.f};
    }

    for (; j + 16 <= e; j += 16) {   // 16 edges: 2 int4 idx + 8 row loads/lane
        const int4* cp = (const int4*)(csr + j + (q2 << 3));
        int4 ra = cp[0];
        int4 rb = cp[1];
        uint4 u0 = *(const uint4*)(hb + (unsigned)ra.x + fso);
        uint4 u1 = *(const uint4*)(hb + (unsigned)ra.y + fso);
        uint4 u2 = *(const uint4*)(hb + (unsigned)ra.z + fso);
        uint4 u3 = *(const uint4*)(hb + (unsigned)ra.w + fso);
        uint4 u4 = *(const uint4*)(hb + (unsigned)rb.x + fso);
        uint4 u5 = *(const uint4*)(hb + (unsigned)rb.y + fso);
        uint4 u6 = *(const uint4*)(hb + (unsigned)rb.z + fso);
        uint4 u7 = *(const uint4*)(hb + (unsigned)rb.w + fso);
        accum8pk(u0, ac); accum8pk(u1, ac);
        accum8pk(u2, ac); accum8pk(u3, ac);
        accum8pk(u4, ac); accum8pk(u5, ac);
        accum8pk(u6, ac); accum8pk(u7, ac);
    }
    if (j + 8 <= e) {                // 8 edges
        int4 ra = *(const int4*)(csr + j + (q2 << 2));
        uint4 u0 = *(const uint4*)(hb + (unsigned)ra.x + fso);
        uint4 u1 = *(const uint4*)(hb + (unsigned)ra.y + fso);
        uint4 u2 = *(const uint4*)(hb + (unsigned)ra.z + fso);
        uint4 u3 = *(const uint4*)(hb + (unsigned)ra.w + fso);
        accum8pk(u0, ac); accum8pk(u1, ac);
        accum8pk(u2, ac); accum8pk(u3, ac);
        j += 8;
    }
    if (j + 4 <= e) {                // 4 edges
        int2 rc = *(const int2*)(csr + j + (q2 << 1));
        uint4 u0 = *(const uint4*)(hb + (unsigned)rc.x + fso);
        uint4 u1 = *(const uint4*)(hb + (unsigned)rc.y + fso);
        accum8pk(u0, ac); accum8pk(u1, ac);
    }

#pragma unroll
    for (int i = 0; i < 4; ++i) {    // reduce over q2 (within the 32-lane half)
        ac[i].x += __shfl_xor(ac[i].x, 16);
        ac[i].y += __shfl_xor(ac[i].y, 16);
    }

    if (q2 == 0) {
        float dn = dinv[node];
        float4 b0 = *(const float4*)(bias + fs * 8);
        float4 b1 = *(const float4*)(bias + fs * 8 + 4);
        float o[8];
        o[0] = dn * ac[0].x + b0.x; o[1] = dn * ac[0].y + b0.y;
        o[2] = dn * ac[1].x + b0.z; o[3] = dn * ac[1].y + b0.w;
        o[4] = dn * ac[2].x + b1.x; o[5] = dn * ac[2].y + b1.y;
        o[6] = dn * ac[3].x + b1.z; o[7] = dn * ac[3].y + b1.w;
        if (RELU) {
#pragma unroll
            for (int i = 0; i < 8; ++i) o[i] = fmaxf(o[i], 0.f);
        }
        uint4 pk;
        pk.x = (unsigned)f2bf(o[0]) | ((unsigned)f2bf(o[1]) << 16);
        pk.y = (unsigned)f2bf(o[2]) | ((unsigned)f2bf(o[3]) << 16);
        pk.z = (unsigned)f2bf(o[4]) | ((unsigned)f2bf(o[5]) << 16);
        pk.w = (unsigned)f2bf(o[6]) | ((unsigned)f2bf(o[7]) << 16);
        outV[(size_t)node * 16 + fs] = pk;
    }
}

// ---------------- pool stage 1: segmented partial sums (bf16 in) -------------
__global__ __launch_bounds__(128) void k_pool_sum(
    const ushort_t* __restrict__ h, const int* __restrict__ batch, int n,
    float* __restrict__ sums) {
    int r0 = blockIdx.x * POOL_CHUNK;
    int r1 = r0 + POOL_CHUNK; if (r1 > n) r1 = n;
    if (r0 >= n) return;
    int t = threadIdx.x;
    int c = t & 63, rr = t >> 6;
    float2 acc = make_float2(0.f, 0.f);
    int g = batch[r0];
    int i = r0;
    while (i < r1) {
        if (i + 8 <= r1 && batch[i + 7] == g) {
#pragma unroll
            for (int b = 0; b < 4; ++b) {
                unsigned u = *(const unsigned*)(h + (size_t)(i + rr + 2 * b) * C_DIM + c * 2);
                acc.x += bf_lo(u); acc.y += bf_hi(u);
            }
            i += 8;
        } else {
            int bi = batch[i];
            if (bi != g) {
                atomicAdd(&sums[(size_t)g * C_DIM + c * 2], acc.x);
                atomicAdd(&sums[(size_t)g * C_DIM + c * 2 + 1], acc.y);
                acc = make_float2(0.f, 0.f); g = bi;
            }
            if (rr == 0) {
                unsigned u = *(const unsigned*)(h + (size_t)i * C_DIM + c * 2);
                acc.x += bf_lo(u); acc.y += bf_hi(u);
            }
            ++i;
        }
    }
    atomicAdd(&sums[(size_t)g * C_DIM + c * 2], acc.x);
    atomicAdd(&sums[(size_t)g * C_DIM + c * 2 + 1], acc.y);
}

// ---------------- pool stage 2: mean + MLP (128->64->1) ----------------
__global__ __launch_bounds__(128) void k_mlp(
    const float* __restrict__ sums, const int* __restrict__ batch, int n,
    const float* __restrict__ Wm1, const float* __restrict__ bm1,
    const float* __restrict__ Wm2, const float* __restrict__ bm2,
    float* __restrict__ out) {
    int g = blockIdx.x;
    int t = threadIdx.x;
    int lo = 0, hi = n;
    while (lo < hi) { int m = (lo + hi) >> 1; if (batch[m] < g) lo = m + 1; else hi = m; }
    int start = lo;
    lo = start; hi = n;
    while (lo < hi) { int m = (lo + hi) >> 1; if (batch[m] < g + 1) lo = m + 1; else hi = m; }
    float cnt = (float)(lo - start);

    float mean = sums[(size_t)g * C_DIM + t] / fmaxf(cnt, 1.0f);

    __shared__ float m_s[128];
    __shared__ float hid[64];
    m_s[t] = mean;
    __syncthreads();
    if (t < 64) {
        float a = bm1[t];
#pragma unroll 4
        for (int k = 0; k < 128; ++k) a += m_s[k] * Wm1[k * 64 + t];
        hid[t] = fmaxf(a, 0.f) * Wm2[t];
    }
    __syncthreads();
    if (t < 64) {
        float v = hid[t];
        for (int off = 32; off > 0; off >>= 1) v += __shfl_down(v, off);
        if (t == 0) out[g] = v + bm2[0];
    }
}

extern "C" void kernel_launch(void* const* d_in, const int* in_sizes, int n_in,
                              void* d_out, int out_size, void* d_ws, size_t ws_size,
                              hipStream_t stream) {
    const float* x     = (const float*)d_in[0];
    const int*   eidx  = (const int*)d_in[1];
    const int*   batch = (const int*)d_in[2];
    const float* W1    = (const float*)d_in[3];
    const float* b1    = (const float*)d_in[4];
    const float* W2    = (const float*)d_in[5];
    const float* b2    = (const float*)d_in[6];
    const float* Wm1   = (const float*)d_in[7];
    const float* bm1   = (const float*)d_in[8];
    const float* Wm2   = (const float*)d_in[9];
    const float* bm2   = (const float*)d_in[10];

    const int N = in_sizes[2];       // 100000
    const int E = in_sizes[1] / 2;   // 1600000 (E % 4 == 0)
    const int G = out_size;          // 512
    const int B = (N + 127) >> BKT_SHIFT;   // 782 buckets

    char* p = (char*)d_ws;
    auto carve = [&](size_t bytes) {
        char* q = p;
        p += (bytes + 255) & ~(size_t)255;
        return q;
    };
    ushort_t* bufT   = (ushort_t*)carve((size_t)(N + 1) * C_DIM * sizeof(ushort_t)); // matmul out (+zero row)
    ushort_t* bufA   = (ushort_t*)carve((size_t)N * C_DIM * sizeof(ushort_t)); // agg out
    float*    dinv   = (float*)   carve((size_t)N * sizeof(float));
    int2*     offs2  = (int2*)    carve((size_t)N * sizeof(int2));
    int*      csr    = (int*)     carve(((size_t)E + 3 * (size_t)N + 64) * sizeof(int));
    int*      counts = (int*)     carve((size_t)CB * MAX_B * sizeof(int));  // block-major
    int*      sstart = (int*)     carve((size_t)CB * MAX_B * sizeof(int));  // block-major
    float*    gsums  = (float*)   carve((size_t)G * C_DIM * sizeof(float));
    uint4*    wf1    = (uint4*)   carve(2048 * sizeof(uint4));
    uint4*    wf2    = (uint4*)   carve(2048 * sizeof(uint4));
    int*      cursor = (int*)     carve(sizeof(int));
    int*      perm   = (int*)     carve((size_t)B * 128 * sizeof(int));
    // epk (packed (src<<7)|node7, 6.4 MB, block-dense) aliases bufT
    int*      epk    = (int*)bufT;

    const int* erow = eidx;
    const int* ecol = eidx + E;
    const int chunk = (ceil_div(E, CB) + 3) & ~3;   // 6252, fits CHUNK_MAX

    // --- CSR build: LDS counting sort, single edge read, dense writes ---
    k_sortchunk<<<CB + 2, 512, 0, stream>>>(erow, ecol, E, chunk, B,
                                            counts, sstart, epk,
                                            W1, W2, wf1, wf2, gsums, G * C_DIM, cursor);
    k_bfinal<<<B, 256, 0, stream>>>(epk, counts, sstart, cursor, chunk, N,
                                    offs2, dinv, csr, perm);

    // --- conv1 ---
    k_matmul_mfma<0><<<ceil_div(N, 64), 256, 0, stream>>>(x, nullptr, wf1, dinv, bufT, N);
    k_aggregate<1><<<B * 16, 256, 0, stream>>>(bufT, offs2, csr, dinv, perm, b1,
                                               (uint4*)bufA, N);
    // --- conv2 ---
    k_matmul_mfma<1><<<ceil_div(N, 64), 256, 0, stream>>>(nullptr, bufA, wf2, dinv, bufT, N);
    k_aggregate<0><<<B * 16, 256, 0, stream>>>(bufT, offs2, csr, dinv, perm, b2,
                                               (uint4*)bufA, N);
    // --- pool (2-stage) + MLP ---
    k_pool_sum<<<ceil_div(N, POOL_CHUNK), 128, 0, stream>>>(bufA, batch, N, gsums);
    k_mlp<<<G, 128, 0, stream>>>(gsums, batch, N, Wm1, bm1, Wm2, bm2, (float*)d_out);
}

// Round 7
// 316.818 us; speedup vs baseline: 1.0356x; 1.0356x over previous
//
#include <hip/hip_runtime.h>
#include <math.h>

#define C_DIM 128
#define POOL_CHUNK 64
#define BKT_SHIFT 7          // 128 nodes per destination bucket
#define MAX_B 1024           // bucket arrays capacity (B = ceil(N/128) = 782)
#define CB 256               // edge chunk blocks
#define CHUNK_MAX 6400       // per-block LDS sort capacity (chunk = 6252)
#define FB_CAP 8192          // bfinal LDS edge-staging capacity (avg bucket ~2048)
typedef unsigned short ushort_t;
typedef __attribute__((ext_vector_type(8))) short short8;
typedef __attribute__((ext_vector_type(4))) float f32x4;
typedef __attribute__((ext_vector_type(2))) float f32x2;  // -> v_pk_add_f32

static inline int ceil_div(int a, int b) { return (a + b - 1) / b; }

// bf16 round-to-nearest-even (unbiased — truncation would bias sums)
__device__ inline ushort_t f2bf(float f) {
    union { float f; unsigned u; } v; v.f = f;
    unsigned r = v.u + 0x7FFFu + ((v.u >> 16) & 1u);
    return (ushort_t)(r >> 16);
}
__device__ inline float bf_lo(unsigned u) {
    union { unsigned v; float f; } c; c.v = u << 16; return c.f;
}
__device__ inline float bf_hi(unsigned u) {
    union { unsigned v; float f; } c; c.v = u & 0xFFFF0000u; return c.f;
}
// packed accumulate: 2 unpack VALU + 1 v_pk_add_f32 per dword
__device__ inline void accum8pk(uint4 u, f32x2 ac[4]) {
    ac[0] += (f32x2){bf_lo(u.x), bf_hi(u.x)};
    ac[1] += (f32x2){bf_lo(u.y), bf_hi(u.y)};
    ac[2] += (f32x2){bf_lo(u.z), bf_hi(u.z)};
    ac[3] += (f32x2){bf_lo(u.w), bf_hi(u.w)};
}

// ============ CSR build: block-local LDS counting sort (dense writes) =======
// 512 threads/block (8 waves/CU at 1 block/CU). SINGLE global edge read.
__global__ __launch_bounds__(512) void k_sortchunk(
    const int* __restrict__ row, const int* __restrict__ col, int E, int chunk,
    int B, int* __restrict__ counts, int* __restrict__ sstart,
    int* __restrict__ epk,
    const float* __restrict__ W1, const float* __restrict__ W2,
    uint4* __restrict__ wf1, uint4* __restrict__ wf2,
    float* __restrict__ gsums, int GC, int* __restrict__ cursor) {
    int t = threadIdx.x, blk = blockIdx.x;
    if (blk >= CB) {   // weight fragment pre-pack
        const float* W = (blk == CB) ? W1 : W2;
        uint4* wf = (blk == CB) ? wf1 : wf2;
        for (int f = t; f < 2048; f += 512) {
            int lane = f & 63, kkn = f >> 6;
            int kk = kkn & 3, nt = kkn >> 2;
            int n = lane & 15, quad = lane >> 4;
            union { ushort_t h[8]; uint4 v; } u;
#pragma unroll
            for (int j = 0; j < 8; ++j)
                u.h[j] = f2bf(W[(size_t)(kk * 32 + quad * 8 + j) * C_DIM + nt * 16 + n]);
            wf[f] = u.v;
        }
        return;
    }
    // zero gsums + cursor (consumers run much later in the stream)
    for (int i = blk * 512 + t; i < GC; i += CB * 512) gsums[i] = 0.f;
    if (blk == 0 && t == 0) *cursor = 0;

    __shared__ int hist[MAX_B];                      // 4 KB
    __shared__ int hscan[MAX_B];                     // 4 KB
    __shared__ int sd[512];                          // 2 KB
    __shared__ __align__(16) int ebuf[CHUNK_MAX];    // 25.6 KB packed (r<<7)|(c&127)
    __shared__ __align__(8)  ushort_t bbuf[CHUNK_MAX]; // 12.8 KB bucket ids
    __shared__ int sorted[CHUNK_MAX];                // 25.6 KB

    for (int i = t; i < B; i += 512) hist[i] = 0;
    __syncthreads();
    int s = blk * chunk;                     // chunk % 4 == 0, E % 4 == 0
    int e = s + chunk; if (e > E) e = E;
    int cnt = e - s;                         // multiple of 4
    for (int i = s + 4 * t; i < e; i += 2048) {
        int4 c = *(const int4*)(col + i);
        int4 r = *(const int4*)(row + i);
        int li = i - s;
        int4 pk;
        pk.x = (r.x << 7) | (c.x & 127);
        pk.y = (r.y << 7) | (c.y & 127);
        pk.z = (r.z << 7) | (c.z & 127);
        pk.w = (r.w << 7) | (c.w & 127);
        *(int4*)&ebuf[li] = pk;
        ushort4 bk;
        bk.x = (ushort_t)(c.x >> BKT_SHIFT);
        bk.y = (ushort_t)(c.y >> BKT_SHIFT);
        bk.z = (ushort_t)(c.z >> BKT_SHIFT);
        bk.w = (ushort_t)(c.w >> BKT_SHIFT);
        *(ushort4*)&bbuf[li] = bk;
        atomicAdd(&hist[bk.x], 1);
        atomicAdd(&hist[bk.y], 1);
        atomicAdd(&hist[bk.z], 1);
        atomicAdd(&hist[bk.w], 1);
    }
    __syncthreads();
    // blocked exclusive scan of hist[0..B) -> hscan  (512 threads x 2 bins)
    {
        int base2 = t * 2;
        int vv[2]; int sum = 0;
#pragma unroll
        for (int j = 0; j < 2; ++j) {
            int idx = base2 + j;
            vv[j] = (idx < B) ? hist[idx] : 0;
            sum += vv[j];
        }
        sd[t] = sum;
        __syncthreads();
        for (int off = 1; off < 512; off <<= 1) {
            int x = (t >= off) ? sd[t - off] : 0;
            __syncthreads();
            sd[t] += x;
            __syncthreads();
        }
        int run = sd[t] - sum;
#pragma unroll
        for (int j = 0; j < 2; ++j) {
            int idx = base2 + j;
            if (idx < B) hscan[idx] = run;
            run += vv[j];
        }
    }
    __syncthreads();
    for (int i = t; i < B; i += 512) {
        counts[(size_t)blk * MAX_B + i] = hist[i];
        sstart[(size_t)blk * MAX_B + i] = hscan[i];
    }
    __syncthreads();
    for (int i = t; i < B; i += 512) hist[i] = hscan[i];  // reuse as cursor
    __syncthreads();
    for (int i = t; i < cnt; i += 512) {
        int pos = atomicAdd(&hist[bbuf[i]], 1);
        sorted[pos] = ebuf[i];
    }
    __syncthreads();
    for (int i = t; i * 4 < cnt; i += 512)
        *(int4*)&epk[s + i * 4] = *(const int4*)&sorted[i * 4];
}

// Final: per bucket, gather its CB segments (serial per-thread staging),
// LDS-stage, per-node count, scan, write (start, aligned-end)+dinv, csr.
// Per-node segments padded to x4 with zero-row (N<<8) entries. Also emits
// in-bucket DEGREE-SORTED perm so the aggregate's 2-nodes-per-wave pairs
// have near-equal trip counts.
__global__ __launch_bounds__(256) void k_bfinal(
    const int* __restrict__ epk, const int* __restrict__ counts,
    const int* __restrict__ sstart, int* __restrict__ cursor,
    int chunk, int N,
    int2* __restrict__ offs2, float* __restrict__ dinv, int* __restrict__ csr,
    int* __restrict__ perm) {
    __shared__ int sh[FB_CAP];       // 32 KB
    __shared__ int sd[256];
    __shared__ int cnt[128];
    __shared__ int pre[128];
    __shared__ int cur[128];
    __shared__ int dbin[64];
    __shared__ int dsc[64];
    __shared__ int dcur[64];
    __shared__ int sbase_s;
    int bkt = blockIdx.x, t = threadIdx.x;
    int base = bkt << BKT_SHIFT;
    int nn = N - base; if (nn > 128) nn = 128;

    int segln = counts[(size_t)t * MAX_B + bkt];
    int gs = t * chunk + sstart[(size_t)t * MAX_B + bkt];
    sd[t] = segln;
    __syncthreads();
    for (int off = 1; off < 256; off <<= 1) {
        int x = (t >= off) ? sd[t - off] : 0;
        __syncthreads();
        sd[t] += x;
        __syncthreads();
    }
    int place = sd[t] - segln;
    int m = sd[255];                 // raw edge count in bucket
    if (t < 128) cnt[t] = 0;
    __syncthreads();

    bool fits = (m <= FB_CAP);
    if (fits) {
        for (int j = 0; j < segln; ++j) {
            int u = epk[gs + j];
            sh[place + j] = u;
            atomicAdd(&cnt[u & 127], 1);
        }
    } else {
        for (int j = 0; j < segln; ++j)
            atomicAdd(&cnt[epk[gs + j] & 127], 1);
    }
    __syncthreads();
    // aligned (multiple-of-4) per-node placement
    if (t < 128) pre[t] = (cnt[t] + 3) & ~3;
    __syncthreads();
    for (int off = 1; off < 128; off <<= 1) {
        int x = (t >= off && t < 128) ? pre[t - off] : 0;
        __syncthreads();
        if (t < 128) pre[t] += x;
        __syncthreads();
    }
    if (t == 127) sbase_s = atomicAdd(cursor, pre[127]);
    __syncthreads();
    int sbase = sbase_s;
    if (t < 128) {
        int c4 = (cnt[t] + 3) & ~3;
        int ex = pre[t] - c4;
        cur[t] = ex;
        if (t < nn) {
            offs2[base + t] = make_int2(sbase + ex, sbase + ex + c4);
            dinv[base + t] = 1.0f / sqrtf((float)cnt[t] + 1.0f);
        }
    }
    __syncthreads();
    if (fits) {
        for (int i = t; i < m; i += 256) {
            int u = sh[i];
            int slot = atomicAdd(&cur[u & 127], 1);
            csr[sbase + slot] = (u >> 7) << 8;      // src * 256B row pitch
        }
    } else {
        for (int j = 0; j < segln; ++j) {
            int u = epk[gs + j];
            int slot = atomicAdd(&cur[u & 127], 1);
            csr[sbase + slot] = (u >> 7) << 8;
        }
    }
    __syncthreads();
    // fill pad slots with the zero-row offset
    if (t < nn) {
        int c4 = (cnt[t] + 3) & ~3;
        int ex = pre[t] - c4;
        int zoff = N << 8;
        for (int k2 = cnt[t]; k2 < c4; ++k2) csr[sbase + ex + k2] = zoff;
    }
    // ---- in-bucket degree sort -> perm (pad slots dup last valid node) ----
    __syncthreads();
    if (t < 64) { dbin[t] = 0; dcur[t] = 0; }
    __syncthreads();
    int deg = 0, bidx = 0, tn = 0;
    if (t < 128) {
        tn = (t < nn) ? t : (nn - 1);
        deg = cnt[tn];
        bidx = deg > 63 ? 63 : deg;
        atomicAdd(&dbin[bidx], 1);
    }
    __syncthreads();
    if (t < 64) dsc[t] = dbin[t];
    __syncthreads();
    for (int off = 1; off < 64; off <<= 1) {
        int x = (t >= off && t < 64) ? dsc[t - off] : 0;
        __syncthreads();
        if (t < 64) dsc[t] += x;
        __syncthreads();
    }
    if (t < 128) {
        int rank = dsc[bidx] - dbin[bidx] + atomicAdd(&dcur[bidx], 1);
        perm[(bkt << 7) + rank] = base + tn;
    }
}

// ============ MFMA matmul [N,128]@[128,128] -> bf16 table, scaled by dinv ===
// 64-row blocks, 49.4 KB LDS -> 3 blocks/CU, 1563 blocks. Also zeroes row N
// (the aggregate's pad target).
template <int ABF16>
__global__ __launch_bounds__(256) void k_matmul_mfma(
    const float* __restrict__ Af, const ushort_t* __restrict__ Abf,
    const uint4* __restrict__ wfrag, const float* __restrict__ dinv,
    ushort_t* __restrict__ Cb, int N) {
    __shared__ uint4 wfs[2048];                       // 32 KB
    __shared__ __align__(16) ushort_t As[64 * 136];   // 17.4 KB (also epilogue)
    int t = threadIdx.x;
    int wv = t >> 6, lane = t & 63;
    int n = lane & 15, quad = lane >> 4;
    int row0 = blockIdx.x * 64;

    for (int i = t; i < 2048; i += 256) wfs[i] = wfrag[i];

    if (ABF16) {
#pragma unroll
        for (int i = 0; i < 4; ++i) {
            int idx = i * 256 + t;
            int r = idx >> 4, c8 = idx & 15;
            int grow = row0 + r; if (grow >= N) grow = N - 1;
            uint4 u = *(const uint4*)(Abf + (size_t)grow * C_DIM + c8 * 8);
            *(uint4*)&As[r * 136 + c8 * 8] = u;
        }
    } else {
#pragma unroll
        for (int i = 0; i < 8; ++i) {
            int idx = i * 256 + t;
            int r = idx >> 5, cq = idx & 31;
            int grow = row0 + r; if (grow >= N) grow = N - 1;
            float4 f = *(const float4*)(Af + (size_t)grow * C_DIM + cq * 4);
            union { ushort_t h[4]; uint2 v; } c;
            c.h[0] = f2bf(f.x); c.h[1] = f2bf(f.y);
            c.h[2] = f2bf(f.z); c.h[3] = f2bf(f.w);
            *(uint2*)&As[r * 136 + cq * 4] = c.v;
        }
    }

    f32x4 acc[8];
#pragma unroll
    for (int i = 0; i < 8; ++i) acc[i] = (f32x4){0.f, 0.f, 0.f, 0.f};

    __syncthreads();

    int rl = wv * 16 + n;
#pragma unroll
    for (int kk = 0; kk < 4; ++kk) {
        union { uint4 v; short8 s; } ca;
        ca.v = *(const uint4*)&As[rl * 136 + kk * 32 + quad * 8];
#pragma unroll
        for (int nt = 0; nt < 8; ++nt) {
            union { uint4 v; short8 s; } cb;
            cb.v = wfs[(nt * 4 + kk) * 64 + lane];
            acc[nt] = __builtin_amdgcn_mfma_f32_16x16x32_bf16(ca.s, cb.s, acc[nt], 0, 0, 0);
        }
    }

    __syncthreads();
#pragma unroll
    for (int reg = 0; reg < 4; ++reg) {
        int lr = wv * 16 + quad * 4 + reg;
        int grow = row0 + lr;
        float sc = dinv[grow < N ? grow : N - 1];
#pragma unroll
        for (int nt = 0; nt < 8; ++nt)
            As[lr * 136 + nt * 16 + n] = f2bf(acc[nt][reg] * sc);
    }
    __syncthreads();
    int rows = N - row0; if (rows > 64) rows = 64;
    for (int idx = t; idx < 16 * 64; idx += 256) {
        int r = idx >> 4, c8 = idx & 15;
        if (r < rows)
            *(uint4*)(Cb + (size_t)(row0 + r) * C_DIM + c8 * 8) =
                *(const uint4*)&As[r * 136 + c8 * 8];
        else if (row0 + r == N)   // zero row N: pad target for aggregate
            *(uint4*)(Cb + (size_t)N * C_DIM + c8 * 8) = (uint4){0, 0, 0, 0};
    }
}

// ---------------- per-node gather-reduce aggregation (bf16 in/out) -----------
// 2 nodes per wave (32 lanes each), nodes ADJACENT IN DEGREE-SORTED ORDER
// (perm) so both halves run near-equal trip counts. Pairs are STRIPED across
// blocks (pair p -> block p&15, wave p>>4) so every block owns one pair from
// each degree quartile -> near-equal block durations (r6's contiguous mapping
// caused a 53% occupancy tail: low blocks finished early, high blocks ran 2x).
// csr segments 4-aligned with zero-row pads: int4 idx loads, no scalar tail.
template <int RELU>
__global__ __launch_bounds__(256) void k_aggregate(
    const ushort_t* __restrict__ hs, const int2* __restrict__ offs2,
    const int* __restrict__ csr, const float* __restrict__ dinv,
    const int* __restrict__ perm, const float* __restrict__ bias,
    uint4* __restrict__ outV, int N) {
    int t = threadIdx.x & 63;
    int half = t >> 5;               // which of the wave's 2 nodes
    int q2 = (t >> 4) & 1;           // edge-slot group within the half
    int fs = t & 15;                 // 16B channel slot (8 channels)
    int bkt = blockIdx.x >> 4;
    // striped pair assignment: pair = wave*16 + block_sub (degree quartiles)
    int pair = ((threadIdx.x >> 6) << 4) + (blockIdx.x & 15);
    int pos = (pair << 1) + half;
    int node = perm[(bkt << 7) + pos];
    const char* hb = (const char*)hs;
    unsigned fso = (unsigned)(fs << 4);
    int2 se = offs2[node];
    int j = se.x, e = se.y;          // e - j is a multiple of 4 (zero-row pads)

    f32x2 ac[4];
    if (q2 == 0) {                   // self-loop
        uint4 u = *(const uint4*)(hb + ((unsigned)node << 8) + fso);
        ac[0] = (f32x2){bf_lo(u.x), bf_hi(u.x)};
        ac[1] = (f32x2){bf_lo(u.y), bf_hi(u.y)};
        ac[2] = (f32x2){bf_lo(u.z), bf_hi(u.z)};
        ac[3] = (f32x2){bf_lo(u.w), bf_hi(u.w)};
    } else {
#pragma unroll
        for (int i = 0; i < 4; ++i) ac[i] = (f32x2){0.f, 0.f};
    }

    for (; j + 16 <= e; j += 16) {   // 16 edges: 2 int4 idx + 8 row loads/lane
        const int4* cp = (const int4*)(csr + j + (q2 << 3));
        int4 ra = cp[0];
        int4 rb = cp[1];
        uint4 u0 = *(const uint4*)(hb + (unsigned)ra.x + fso);
        uint4 u1 = *(const uint4*)(hb + (unsigned)ra.y + fso);
        uint4 u2 = *(const uint4*)(hb + (unsigned)ra.z + fso);
        uint4 u3 = *(const uint4*)(hb + (unsigned)ra.w + fso);
        uint4 u4 = *(const uint4*)(hb + (unsigned)rb.x + fso);
        uint4 u5 = *(const uint4*)(hb + (unsigned)rb.y + fso);
        uint4 u6 = *(const uint4*)(hb + (unsigned)rb.z + fso);
        uint4 u7 = *(const uint4*)(hb + (unsigned)rb.w + fso);
        accum8pk(u0, ac); accum8pk(u1, ac);
        accum8pk(u2, ac); accum8pk(u3, ac);
        accum8pk(u4, ac); accum8pk(u5, ac);
        accum8pk(u6, ac); accum8pk(u7, ac);
    }
    if (j + 8 <= e) {                // 8 edges
        int4 ra = *(const int4*)(csr + j + (q2 << 2));
        uint4 u0 = *(const uint4*)(hb + (unsigned)ra.x + fso);
        uint4 u1 = *(const uint4*)(hb + (unsigned)ra.y + fso);
        uint4 u2 = *(const uint4*)(hb + (unsigned)ra.z + fso);
        uint4 u3 = *(const uint4*)(hb + (unsigned)ra.w + fso);
        accum8pk(u0, ac); accum8pk(u1, ac);
        accum8pk(u2, ac); accum8pk(u3, ac);
        j += 8;
    }
    if (j + 4 <= e) {                // 4 edges
        int2 rc = *(const int2*)(csr + j + (q2 << 1));
        uint4 u0 = *(const uint4*)(hb + (unsigned)rc.x + fso);
        uint4 u1 = *(const uint4*)(hb + (unsigned)rc.y + fso);
        accum8pk(u0, ac); accum8pk(u1, ac);
    }

#pragma unroll
    for (int i = 0; i < 4; ++i) {    // reduce over q2 (within the 32-lane half)
        ac[i].x += __shfl_xor(ac[i].x, 16);
        ac[i].y += __shfl_xor(ac[i].y, 16);
    }

    if (q2 == 0) {
        float dn = dinv[node];
        float4 b0 = *(const float4*)(bias + fs * 8);
        float4 b1 = *(const float4*)(bias + fs * 8 + 4);
        float o[8];
        o[0] = dn * ac[0].x + b0.x; o[1] = dn * ac[0].y + b0.y;
        o[2] = dn * ac[1].x + b0.z; o[3] = dn * ac[1].y + b0.w;
        o[4] = dn * ac[2].x + b1.x; o[5] = dn * ac[2].y + b1.y;
        o[6] = dn * ac[3].x + b1.z; o[7] = dn * ac[3].y + b1.w;
        if (RELU) {
#pragma unroll
            for (int i = 0; i < 8; ++i) o[i] = fmaxf(o[i], 0.f);
        }
        uint4 pk;
        pk.x = (unsigned)f2bf(o[0]) | ((unsigned)f2bf(o[1]) << 16);
        pk.y = (unsigned)f2bf(o[2]) | ((unsigned)f2bf(o[3]) << 16);
        pk.z = (unsigned)f2bf(o[4]) | ((unsigned)f2bf(o[5]) << 16);
        pk.w = (unsigned)f2bf(o[6]) | ((unsigned)f2bf(o[7]) << 16);
        outV[(size_t)node * 16 + fs] = pk;
    }
}

// ---------------- pool stage 1: segmented partial sums (bf16 in) -------------
__global__ __launch_bounds__(128) void k_pool_sum(
    const ushort_t* __restrict__ h, const int* __restrict__ batch, int n,
    float* __restrict__ sums) {
    int r0 = blockIdx.x * POOL_CHUNK;
    int r1 = r0 + POOL_CHUNK; if (r1 > n) r1 = n;
    if (r0 >= n) return;
    int t = threadIdx.x;
    int c = t & 63, rr = t >> 6;
    float2 acc = make_float2(0.f, 0.f);
    int g = batch[r0];
    int i = r0;
    while (i < r1) {
        if (i + 8 <= r1 && batch[i + 7] == g) {
#pragma unroll
            for (int b = 0; b < 4; ++b) {
                unsigned u = *(const unsigned*)(h + (size_t)(i + rr + 2 * b) * C_DIM + c * 2);
                acc.x += bf_lo(u); acc.y += bf_hi(u);
            }
            i += 8;
        } else {
            int bi = batch[i];
            if (bi != g) {
                atomicAdd(&sums[(size_t)g * C_DIM + c * 2], acc.x);
                atomicAdd(&sums[(size_t)g * C_DIM + c * 2 + 1], acc.y);
                acc = make_float2(0.f, 0.f); g = bi;
            }
            if (rr == 0) {
                unsigned u = *(const unsigned*)(h + (size_t)i * C_DIM + c * 2);
                acc.x += bf_lo(u); acc.y += bf_hi(u);
            }
            ++i;
        }
    }
    atomicAdd(&sums[(size_t)g * C_DIM + c * 2], acc.x);
    atomicAdd(&sums[(size_t)g * C_DIM + c * 2 + 1], acc.y);
}

// ---------------- pool stage 2: mean + MLP (128->64->1) ----------------
__global__ __launch_bounds__(128) void k_mlp(
    const float* __restrict__ sums, const int* __restrict__ batch, int n,
    const float* __restrict__ Wm1, const float* __restrict__ bm1,
    const float* __restrict__ Wm2, const float* __restrict__ bm2,
    float* __restrict__ out) {
    int g = blockIdx.x;
    int t = threadIdx.x;
    int lo = 0, hi = n;
    while (lo < hi) { int m = (lo + hi) >> 1; if (batch[m] < g) lo = m + 1; else hi = m; }
    int start = lo;
    lo = start; hi = n;
    while (lo < hi) { int m = (lo + hi) >> 1; if (batch[m] < g + 1) lo = m + 1; else hi = m; }
    float cnt = (float)(lo - start);

    float mean = sums[(size_t)g * C_DIM + t] / fmaxf(cnt, 1.0f);

    __shared__ float m_s[128];
    __shared__ float hid[64];
    m_s[t] = mean;
    __syncthreads();
    if (t < 64) {
        float a = bm1[t];
#pragma unroll 4
        for (int k = 0; k < 128; ++k) a += m_s[k] * Wm1[k * 64 + t];
        hid[t] = fmaxf(a, 0.f) * Wm2[t];
    }
    __syncthreads();
    if (t < 64) {
        float v = hid[t];
        for (int off = 32; off > 0; off >>= 1) v += __shfl_down(v, off);
        if (t == 0) out[g] = v + bm2[0];
    }
}

extern "C" void kernel_launch(void* const* d_in, const int* in_sizes, int n_in,
                              void* d_out, int out_size, void* d_ws, size_t ws_size,
                              hipStream_t stream) {
    const float* x     = (const float*)d_in[0];
    const int*   eidx  = (const int*)d_in[1];
    const int*   batch = (const int*)d_in[2];
    const float* W1    = (const float*)d_in[3];
    const float* b1    = (const float*)d_in[4];
    const float* W2    = (const float*)d_in[5];
    const float* b2    = (const float*)d_in[6];
    const float* Wm1   = (const float*)d_in[7];
    const float* bm1   = (const float*)d_in[8];
    const float* Wm2   = (const float*)d_in[9];
    const float* bm2   = (const float*)d_in[10];

    const int N = in_sizes[2];       // 100000
    const int E = in_sizes[1] / 2;   // 1600000 (E % 4 == 0)
    const int G = out_size;          // 512
    const int B = (N + 127) >> BKT_SHIFT;   // 782 buckets

    char* p = (char*)d_ws;
    auto carve = [&](size_t bytes) {
        char* q = p;
        p += (bytes + 255) & ~(size_t)255;
        return q;
    };
    ushort_t* bufT   = (ushort_t*)carve((size_t)(N + 1) * C_DIM * sizeof(ushort_t)); // matmul out (+zero row)
    ushort_t* bufA   = (ushort_t*)carve((size_t)N * C_DIM * sizeof(ushort_t)); // agg out
    float*    dinv   = (float*)   carve((size_t)N * sizeof(float));
    int2*     offs2  = (int2*)    carve((size_t)N * sizeof(int2));
    int*      csr    = (int*)     carve(((size_t)E + 3 * (size_t)N + 64) * sizeof(int));
    int*      counts = (int*)     carve((size_t)CB * MAX_B * sizeof(int));  // block-major
    int*      sstart = (int*)     carve((size_t)CB * MAX_B * sizeof(int));  // block-major
    float*    gsums  = (float*)   carve((size_t)G * C_DIM * sizeof(float));
    uint4*    wf1    = (uint4*)   carve(2048 * sizeof(uint4));
    uint4*    wf2    = (uint4*)   carve(2048 * sizeof(uint4));
    int*      cursor = (int*)     carve(sizeof(int));
    int*      perm   = (int*)     carve((size_t)B * 128 * sizeof(int));
    // epk (packed (src<<7)|node7, 6.4 MB, block-dense) aliases bufT
    int*      epk    = (int*)bufT;

    const int* erow = eidx;
    const int* ecol = eidx + E;
    const int chunk = (ceil_div(E, CB) + 3) & ~3;   // 6252, fits CHUNK_MAX

    // --- CSR build: LDS counting sort, single edge read, dense writes ---
    k_sortchunk<<<CB + 2, 512, 0, stream>>>(erow, ecol, E, chunk, B,
                                            counts, sstart, epk,
                                            W1, W2, wf1, wf2, gsums, G * C_DIM, cursor);
    k_bfinal<<<B, 256, 0, stream>>>(epk, counts, sstart, cursor, chunk, N,
                                    offs2, dinv, csr, perm);

    // --- conv1 ---
    k_matmul_mfma<0><<<ceil_div(N, 64), 256, 0, stream>>>(x, nullptr, wf1, dinv, bufT, N);
    k_aggregate<1><<<B * 16, 256, 0, stream>>>(bufT, offs2, csr, dinv, perm, b1,
                                               (uint4*)bufA, N);
    // --- conv2 ---
    k_matmul_mfma<1><<<ceil_div(N, 64), 256, 0, stream>>>(nullptr, bufA, wf2, dinv, bufT, N);
    k_aggregate<0><<<B * 16, 256, 0, stream>>>(bufT, offs2, csr, dinv, perm, b2,
                                               (uint4*)bufA, N);
    // --- pool (2-stage) + MLP ---
    k_pool_sum<<<ceil_div(N, POOL_CHUNK), 128, 0, stream>>>(bufA, batch, N, gsums);
    k_mlp<<<G, 128, 0, stream>>>(gsums, batch, N, Wm1, bm1, Wm2, bm2, (float*)d_out);
}

// Round 8
// 304.113 us; speedup vs baseline: 1.0789x; 1.0418x over previous
//
#include <hip/hip_runtime.h>
#include <math.h>

#define C_DIM 128
#define POOL_CHUNK 64
#define BKT_SHIFT 7          // 128 nodes per destination bucket
#define MAX_B 1024           // bucket arrays capacity (B = ceil(N/128) = 782)
#define CB 256               // edge chunk blocks
#define CHUNK_MAX 6400       // per-block LDS sort capacity (chunk = 6252)
#define FB_CAP 8192          // bfinal LDS edge-staging capacity (avg bucket ~2048)
typedef unsigned short ushort_t;
typedef __attribute__((ext_vector_type(8))) short short8;
typedef __attribute__((ext_vector_type(4))) float f32x4;
typedef __attribute__((ext_vector_type(2))) float f32x2;  // -> v_pk_add_f32

static inline int ceil_div(int a, int b) { return (a + b - 1) / b; }

// bf16 round-to-nearest-even (unbiased — truncation would bias sums)
__device__ inline ushort_t f2bf(float f) {
    union { float f; unsigned u; } v; v.f = f;
    unsigned r = v.u + 0x7FFFu + ((v.u >> 16) & 1u);
    return (ushort_t)(r >> 16);
}
__device__ inline float bf_lo(unsigned u) {
    union { unsigned v; float f; } c; c.v = u << 16; return c.f;
}
__device__ inline float bf_hi(unsigned u) {
    union { unsigned v; float f; } c; c.v = u & 0xFFFF0000u; return c.f;
}
// packed accumulate: 2 unpack VALU + 1 v_pk_add_f32 per dword
__device__ inline void accum8pk(uint4 u, f32x2 ac[4]) {
    ac[0] += (f32x2){bf_lo(u.x), bf_hi(u.x)};
    ac[1] += (f32x2){bf_lo(u.y), bf_hi(u.y)};
    ac[2] += (f32x2){bf_lo(u.z), bf_hi(u.z)};
    ac[3] += (f32x2){bf_lo(u.w), bf_hi(u.w)};
}

// ============ CSR build: block-local LDS counting sort (dense writes) =======
// 512 threads/block (8 waves/CU at 1 block/CU). SINGLE global edge read.
__global__ __launch_bounds__(512) void k_sortchunk(
    const int* __restrict__ row, const int* __restrict__ col, int E, int chunk,
    int B, int* __restrict__ counts, int* __restrict__ sstart,
    int* __restrict__ epk,
    const float* __restrict__ W1, const float* __restrict__ W2,
    uint4* __restrict__ wf1, uint4* __restrict__ wf2,
    float* __restrict__ gsums, int GC, int* __restrict__ cursor) {
    int t = threadIdx.x, blk = blockIdx.x;
    if (blk >= CB) {   // weight fragment pre-pack
        const float* W = (blk == CB) ? W1 : W2;
        uint4* wf = (blk == CB) ? wf1 : wf2;
        for (int f = t; f < 2048; f += 512) {
            int lane = f & 63, kkn = f >> 6;
            int kk = kkn & 3, nt = kkn >> 2;
            int n = lane & 15, quad = lane >> 4;
            union { ushort_t h[8]; uint4 v; } u;
#pragma unroll
            for (int j = 0; j < 8; ++j)
                u.h[j] = f2bf(W[(size_t)(kk * 32 + quad * 8 + j) * C_DIM + nt * 16 + n]);
            wf[f] = u.v;
        }
        return;
    }
    // zero gsums + cursor (consumers run much later in the stream)
    for (int i = blk * 512 + t; i < GC; i += CB * 512) gsums[i] = 0.f;
    if (blk == 0 && t == 0) *cursor = 0;

    __shared__ int hist[MAX_B];                      // 4 KB
    __shared__ int hscan[MAX_B];                     // 4 KB
    __shared__ int sd[512];                          // 2 KB
    __shared__ __align__(16) int ebuf[CHUNK_MAX];    // 25.6 KB packed (r<<7)|(c&127)
    __shared__ __align__(8)  ushort_t bbuf[CHUNK_MAX]; // 12.8 KB bucket ids
    __shared__ int sorted[CHUNK_MAX];                // 25.6 KB

    for (int i = t; i < B; i += 512) hist[i] = 0;
    __syncthreads();
    int s = blk * chunk;                     // chunk % 4 == 0, E % 4 == 0
    int e = s + chunk; if (e > E) e = E;
    int cnt = e - s;                         // multiple of 4
    for (int i = s + 4 * t; i < e; i += 2048) {
        int4 c = *(const int4*)(col + i);
        int4 r = *(const int4*)(row + i);
        int li = i - s;
        int4 pk;
        pk.x = (r.x << 7) | (c.x & 127);
        pk.y = (r.y << 7) | (c.y & 127);
        pk.z = (r.z << 7) | (c.z & 127);
        pk.w = (r.w << 7) | (c.w & 127);
        *(int4*)&ebuf[li] = pk;
        ushort4 bk;
        bk.x = (ushort_t)(c.x >> BKT_SHIFT);
        bk.y = (ushort_t)(c.y >> BKT_SHIFT);
        bk.z = (ushort_t)(c.z >> BKT_SHIFT);
        bk.w = (ushort_t)(c.w >> BKT_SHIFT);
        *(ushort4*)&bbuf[li] = bk;
        atomicAdd(&hist[bk.x], 1);
        atomicAdd(&hist[bk.y], 1);
        atomicAdd(&hist[bk.z], 1);
        atomicAdd(&hist[bk.w], 1);
    }
    __syncthreads();
    // blocked exclusive scan of hist[0..B) -> hscan  (512 threads x 2 bins)
    {
        int base2 = t * 2;
        int vv[2]; int sum = 0;
#pragma unroll
        for (int j = 0; j < 2; ++j) {
            int idx = base2 + j;
            vv[j] = (idx < B) ? hist[idx] : 0;
            sum += vv[j];
        }
        sd[t] = sum;
        __syncthreads();
        for (int off = 1; off < 512; off <<= 1) {
            int x = (t >= off) ? sd[t - off] : 0;
            __syncthreads();
            sd[t] += x;
            __syncthreads();
        }
        int run = sd[t] - sum;
#pragma unroll
        for (int j = 0; j < 2; ++j) {
            int idx = base2 + j;
            if (idx < B) hscan[idx] = run;
            run += vv[j];
        }
    }
    __syncthreads();
    for (int i = t; i < B; i += 512) {
        counts[(size_t)blk * MAX_B + i] = hist[i];
        sstart[(size_t)blk * MAX_B + i] = hscan[i];
    }
    __syncthreads();
    for (int i = t; i < B; i += 512) hist[i] = hscan[i];  // reuse as cursor
    __syncthreads();
    for (int i = t; i < cnt; i += 512) {
        int pos = atomicAdd(&hist[bbuf[i]], 1);
        sorted[pos] = ebuf[i];
    }
    __syncthreads();
    for (int i = t; i * 4 < cnt; i += 512)
        *(int4*)&epk[s + i * 4] = *(const int4*)&sorted[i * 4];
}

// Final: per bucket, gather its CB segments, LDS-stage, per-node count, scan,
// write (start, aligned-end)+dinv, csr. Per-node segments padded to x4 with
// zero-row (N<<8) entries so the aggregate can use aligned int4 idx loads and
// clamped flat windows. csr stores PRE-SCALED byte offsets (src*256).
__global__ __launch_bounds__(256) void k_bfinal(
    const int* __restrict__ epk, const int* __restrict__ counts,
    const int* __restrict__ sstart, int* __restrict__ cursor,
    int chunk, int N,
    int2* __restrict__ offs2, float* __restrict__ dinv, int* __restrict__ csr) {
    __shared__ int sh[FB_CAP];
    __shared__ int sd[256];
    __shared__ int cnt[128];
    __shared__ int pre[128];
    __shared__ int cur[128];
    __shared__ int sbase_s;
    int bkt = blockIdx.x, t = threadIdx.x;
    int base = bkt << BKT_SHIFT;
    int nn = N - base; if (nn > 128) nn = 128;

    int segln = counts[(size_t)t * MAX_B + bkt];
    int gs = t * chunk + sstart[(size_t)t * MAX_B + bkt];
    sd[t] = segln;
    __syncthreads();
    for (int off = 1; off < 256; off <<= 1) {
        int x = (t >= off) ? sd[t - off] : 0;
        __syncthreads();
        sd[t] += x;
        __syncthreads();
    }
    int place = sd[t] - segln;
    int m = sd[255];                 // raw edge count in bucket (LDS decision)
    if (t < 128) cnt[t] = 0;
    __syncthreads();

    bool fits = (m <= FB_CAP);
    if (fits) {
        for (int j = 0; j < segln; ++j) {
            int u = epk[gs + j];
            sh[place + j] = u;
            atomicAdd(&cnt[u & 127], 1);
        }
    } else {
        for (int j = 0; j < segln; ++j)
            atomicAdd(&cnt[epk[gs + j] & 127], 1);
    }
    __syncthreads();
    // aligned (multiple-of-4) per-node placement
    if (t < 128) pre[t] = (cnt[t] + 3) & ~3;
    __syncthreads();
    for (int off = 1; off < 128; off <<= 1) {
        int x = (t >= off && t < 128) ? pre[t - off] : 0;
        __syncthreads();
        if (t < 128) pre[t] += x;
        __syncthreads();
    }
    if (t == 127) sbase_s = atomicAdd(cursor, pre[127]);
    __syncthreads();
    int sbase = sbase_s;
    if (t < 128) {
        int c4 = (cnt[t] + 3) & ~3;
        int ex = pre[t] - c4;
        cur[t] = ex;
        if (t < nn) {
            offs2[base + t] = make_int2(sbase + ex, sbase + ex + c4);
            dinv[base + t] = 1.0f / sqrtf((float)cnt[t] + 1.0f);
        }
    }
    __syncthreads();
    if (fits) {
        for (int i = t; i < m; i += 256) {
            int u = sh[i];
            int slot = atomicAdd(&cur[u & 127], 1);
            csr[sbase + slot] = (u >> 7) << 8;      // src * 256B row pitch
        }
    } else {
        for (int j = 0; j < segln; ++j) {
            int u = epk[gs + j];
            int slot = atomicAdd(&cur[u & 127], 1);
            csr[sbase + slot] = (u >> 7) << 8;
        }
    }
    __syncthreads();
    // fill pad slots with the zero-row offset
    if (t < nn) {
        int c4 = (cnt[t] + 3) & ~3;
        int ex = pre[t] - c4;
        int zoff = N << 8;
        for (int k2 = cnt[t]; k2 < c4; ++k2) csr[sbase + ex + k2] = zoff;
    }
}

// ============ MFMA matmul [N,128]@[128,128] -> bf16 table, scaled by dinv ===
// 64-row blocks, 49.4 KB LDS -> 3 blocks/CU, 1563 blocks. Also zeroes row N
// (the aggregate's pad/clamp target).
template <int ABF16>
__global__ __launch_bounds__(256) void k_matmul_mfma(
    const float* __restrict__ Af, const ushort_t* __restrict__ Abf,
    const uint4* __restrict__ wfrag, const float* __restrict__ dinv,
    ushort_t* __restrict__ Cb, int N) {
    __shared__ uint4 wfs[2048];                       // 32 KB
    __shared__ __align__(16) ushort_t As[64 * 136];   // 17.4 KB (also epilogue)
    int t = threadIdx.x;
    int wv = t >> 6, lane = t & 63;
    int n = lane & 15, quad = lane >> 4;
    int row0 = blockIdx.x * 64;

    for (int i = t; i < 2048; i += 256) wfs[i] = wfrag[i];

    if (ABF16) {
#pragma unroll
        for (int i = 0; i < 4; ++i) {
            int idx = i * 256 + t;
            int r = idx >> 4, c8 = idx & 15;
            int grow = row0 + r; if (grow >= N) grow = N - 1;
            uint4 u = *(const uint4*)(Abf + (size_t)grow * C_DIM + c8 * 8);
            *(uint4*)&As[r * 136 + c8 * 8] = u;
        }
    } else {
#pragma unroll
        for (int i = 0; i < 8; ++i) {
            int idx = i * 256 + t;
            int r = idx >> 5, cq = idx & 31;
            int grow = row0 + r; if (grow >= N) grow = N - 1;
            float4 f = *(const float4*)(Af + (size_t)grow * C_DIM + cq * 4);
            union { ushort_t h[4]; uint2 v; } c;
            c.h[0] = f2bf(f.x); c.h[1] = f2bf(f.y);
            c.h[2] = f2bf(f.z); c.h[3] = f2bf(f.w);
            *(uint2*)&As[r * 136 + cq * 4] = c.v;
        }
    }

    f32x4 acc[8];
#pragma unroll
    for (int i = 0; i < 8; ++i) acc[i] = (f32x4){0.f, 0.f, 0.f, 0.f};

    __syncthreads();

    int rl = wv * 16 + n;
#pragma unroll
    for (int kk = 0; kk < 4; ++kk) {
        union { uint4 v; short8 s; } ca;
        ca.v = *(const uint4*)&As[rl * 136 + kk * 32 + quad * 8];
#pragma unroll
        for (int nt = 0; nt < 8; ++nt) {
            union { uint4 v; short8 s; } cb;
            cb.v = wfs[(nt * 4 + kk) * 64 + lane];
            acc[nt] = __builtin_amdgcn_mfma_f32_16x16x32_bf16(ca.s, cb.s, acc[nt], 0, 0, 0);
        }
    }

    __syncthreads();
#pragma unroll
    for (int reg = 0; reg < 4; ++reg) {
        int lr = wv * 16 + quad * 4 + reg;
        int grow = row0 + lr;
        float sc = dinv[grow < N ? grow : N - 1];
#pragma unroll
        for (int nt = 0; nt < 8; ++nt)
            As[lr * 136 + nt * 16 + n] = f2bf(acc[nt][reg] * sc);
    }
    __syncthreads();
    int rows = N - row0; if (rows > 64) rows = 64;
    for (int idx = t; idx < 16 * 64; idx += 256) {
        int r = idx >> 4, c8 = idx & 15;
        if (r < rows)
            *(uint4*)(Cb + (size_t)(row0 + r) * C_DIM + c8 * 8) =
                *(const uint4*)&As[r * 136 + c8 * 8];
        else if (row0 + r == N)   // zero row N: pad/clamp target for aggregate
            *(uint4*)(Cb + (size_t)N * C_DIM + c8 * 8) = (uint4){0, 0, 0, 0};
    }
}

// ---------------- per-node gather-reduce aggregation (bf16 in/out) -----------
// 2 nodes per wave (32 lanes each), plain r4 node order (perm experiments r6/r7
// measured net-negative). FLAT 24-EDGE WINDOW: all idx quads for edges
// [j, j+24) load in ONE latency window (3 int4 per 16-lane group), invalid
// quads clamped to the zero row (cached, ~free), then 12 row-gathers + accum.
// Covers 98.2% of nodes (Poisson-16) with exactly 2 latency windows instead of
// the former 2-4 (loop round + tails). Remainder (deg>24) falls to the loop.
template <int RELU>
__global__ __launch_bounds__(256) void k_aggregate(
    const ushort_t* __restrict__ hs, const int2* __restrict__ offs2,
    const int* __restrict__ csr, const float* __restrict__ dinv,
    const float* __restrict__ bias, uint4* __restrict__ outV, int N) {
    int t = threadIdx.x & 63;
    int half = t >> 5;               // which of the wave's 2 nodes
    int q2 = (t >> 4) & 1;           // edge-slot group within the half
    int fs = t & 15;                 // 16B channel slot (8 channels)
    int node = (blockIdx.x << 3) + ((threadIdx.x >> 6) << 1) + half;
    bool valid = node < N;
    if (!valid) node = N - 1;
    const char* hb = (const char*)hs;
    unsigned fso = (unsigned)(fs << 4);
    int2 se = offs2[node];
    int j = se.x, e = se.y;          // e - j is a multiple of 4 (zero-row pads)
    int zoff = N << 8;               // zero-row byte offset (clamp target)

    f32x2 ac[4];
    if (q2 == 0) {                   // self-loop
        uint4 u = *(const uint4*)(hb + ((unsigned)node << 8) + fso);
        ac[0] = (f32x2){bf_lo(u.x), bf_hi(u.x)};
        ac[1] = (f32x2){bf_lo(u.y), bf_hi(u.y)};
        ac[2] = (f32x2){bf_lo(u.z), bf_hi(u.z)};
        ac[3] = (f32x2){bf_lo(u.w), bf_hi(u.w)};
    } else {
#pragma unroll
        for (int i = 0; i < 4; ++i) ac[i] = (f32x2){0.f, 0.f};
    }

    // ---- flat fast window: edges [j, j+24), clamped ----
    // group q2 owns quads at j+q2*8, j+q2*8+4 (first 16) and j+16+q2*4.
    {
        const int4* bp = (const int4*)(csr + j + (q2 << 3));
        int4 ia = bp[0];
        int4 ib = bp[1];
        int4 ic = *(const int4*)(csr + j + 16 + (q2 << 2));
        int sA = j + (q2 << 3);
        bool vA = sA < e, vB = sA + 4 < e, vC = (j + 16 + (q2 << 2)) < e;
        ia.x = vA ? ia.x : zoff; ia.y = vA ? ia.y : zoff;
        ia.z = vA ? ia.z : zoff; ia.w = vA ? ia.w : zoff;
        ib.x = vB ? ib.x : zoff; ib.y = vB ? ib.y : zoff;
        ib.z = vB ? ib.z : zoff; ib.w = vB ? ib.w : zoff;
        ic.x = vC ? ic.x : zoff; ic.y = vC ? ic.y : zoff;
        ic.z = vC ? ic.z : zoff; ic.w = vC ? ic.w : zoff;
        uint4 u0 = *(const uint4*)(hb + (unsigned)ia.x + fso);
        uint4 u1 = *(const uint4*)(hb + (unsigned)ia.y + fso);
        uint4 u2 = *(const uint4*)(hb + (unsigned)ia.z + fso);
        uint4 u3 = *(const uint4*)(hb + (unsigned)ia.w + fso);
        uint4 u4 = *(const uint4*)(hb + (unsigned)ib.x + fso);
        uint4 u5 = *(const uint4*)(hb + (unsigned)ib.y + fso);
        uint4 u6 = *(const uint4*)(hb + (unsigned)ib.z + fso);
        uint4 u7 = *(const uint4*)(hb + (unsigned)ib.w + fso);
        uint4 w0 = *(const uint4*)(hb + (unsigned)ic.x + fso);
        uint4 w1 = *(const uint4*)(hb + (unsigned)ic.y + fso);
        uint4 w2 = *(const uint4*)(hb + (unsigned)ic.z + fso);
        uint4 w3 = *(const uint4*)(hb + (unsigned)ic.w + fso);
        accum8pk(u0, ac); accum8pk(u1, ac);
        accum8pk(u2, ac); accum8pk(u3, ac);
        accum8pk(u4, ac); accum8pk(u5, ac);
        accum8pk(u6, ac); accum8pk(u7, ac);
        accum8pk(w0, ac); accum8pk(w1, ac);
        accum8pk(w2, ac); accum8pk(w3, ac);
    }

    // ---- slow path for deg>24 (~1.8% of nodes) ----
    int j2 = j + 24;
    for (; j2 + 16 <= e; j2 += 16) {
        const int4* cp = (const int4*)(csr + j2 + (q2 << 3));
        int4 ra = cp[0];
        int4 rb = cp[1];
        uint4 u0 = *(const uint4*)(hb + (unsigned)ra.x + fso);
        uint4 u1 = *(const uint4*)(hb + (unsigned)ra.y + fso);
        uint4 u2 = *(const uint4*)(hb + (unsigned)ra.z + fso);
        uint4 u3 = *(const uint4*)(hb + (unsigned)ra.w + fso);
        uint4 u4 = *(const uint4*)(hb + (unsigned)rb.x + fso);
        uint4 u5 = *(const uint4*)(hb + (unsigned)rb.y + fso);
        uint4 u6 = *(const uint4*)(hb + (unsigned)rb.z + fso);
        uint4 u7 = *(const uint4*)(hb + (unsigned)rb.w + fso);
        accum8pk(u0, ac); accum8pk(u1, ac);
        accum8pk(u2, ac); accum8pk(u3, ac);
        accum8pk(u4, ac); accum8pk(u5, ac);
        accum8pk(u6, ac); accum8pk(u7, ac);
    }
    if (j2 + 8 <= e) {
        int4 ra = *(const int4*)(csr + j2 + (q2 << 2));
        uint4 u0 = *(const uint4*)(hb + (unsigned)ra.x + fso);
        uint4 u1 = *(const uint4*)(hb + (unsigned)ra.y + fso);
        uint4 u2 = *(const uint4*)(hb + (unsigned)ra.z + fso);
        uint4 u3 = *(const uint4*)(hb + (unsigned)ra.w + fso);
        accum8pk(u0, ac); accum8pk(u1, ac);
        accum8pk(u2, ac); accum8pk(u3, ac);
        j2 += 8;
    }
    if (j2 + 4 <= e) {
        int2 rc = *(const int2*)(csr + j2 + (q2 << 1));
        uint4 u0 = *(const uint4*)(hb + (unsigned)rc.x + fso);
        uint4 u1 = *(const uint4*)(hb + (unsigned)rc.y + fso);
        accum8pk(u0, ac); accum8pk(u1, ac);
    }

#pragma unroll
    for (int i = 0; i < 4; ++i) {    // reduce over q2 (within the 32-lane half)
        ac[i].x += __shfl_xor(ac[i].x, 16);
        ac[i].y += __shfl_xor(ac[i].y, 16);
    }

    if (q2 == 0 && valid) {
        float dn = dinv[node];
        float4 b0 = *(const float4*)(bias + fs * 8);
        float4 b1 = *(const float4*)(bias + fs * 8 + 4);
        float o[8];
        o[0] = dn * ac[0].x + b0.x; o[1] = dn * ac[0].y + b0.y;
        o[2] = dn * ac[1].x + b0.z; o[3] = dn * ac[1].y + b0.w;
        o[4] = dn * ac[2].x + b1.x; o[5] = dn * ac[2].y + b1.y;
        o[6] = dn * ac[3].x + b1.z; o[7] = dn * ac[3].y + b1.w;
        if (RELU) {
#pragma unroll
            for (int i = 0; i < 8; ++i) o[i] = fmaxf(o[i], 0.f);
        }
        uint4 pk;
        pk.x = (unsigned)f2bf(o[0]) | ((unsigned)f2bf(o[1]) << 16);
        pk.y = (unsigned)f2bf(o[2]) | ((unsigned)f2bf(o[3]) << 16);
        pk.z = (unsigned)f2bf(o[4]) | ((unsigned)f2bf(o[5]) << 16);
        pk.w = (unsigned)f2bf(o[6]) | ((unsigned)f2bf(o[7]) << 16);
        outV[(size_t)node * 16 + fs] = pk;
    }
}

// ---------------- pool stage 1: segmented partial sums (bf16 in) -------------
__global__ __launch_bounds__(128) void k_pool_sum(
    const ushort_t* __restrict__ h, const int* __restrict__ batch, int n,
    float* __restrict__ sums) {
    int r0 = blockIdx.x * POOL_CHUNK;
    int r1 = r0 + POOL_CHUNK; if (r1 > n) r1 = n;
    if (r0 >= n) return;
    int t = threadIdx.x;
    int c = t & 63, rr = t >> 6;
    float2 acc = make_float2(0.f, 0.f);
    int g = batch[r0];
    int i = r0;
    while (i < r1) {
        if (i + 8 <= r1 && batch[i + 7] == g) {
#pragma unroll
            for (int b = 0; b < 4; ++b) {
                unsigned u = *(const unsigned*)(h + (size_t)(i + rr + 2 * b) * C_DIM + c * 2);
                acc.x += bf_lo(u); acc.y += bf_hi(u);
            }
            i += 8;
        } else {
            int bi = batch[i];
            if (bi != g) {
                atomicAdd(&sums[(size_t)g * C_DIM + c * 2], acc.x);
                atomicAdd(&sums[(size_t)g * C_DIM + c * 2 + 1], acc.y);
                acc = make_float2(0.f, 0.f); g = bi;
            }
            if (rr == 0) {
                unsigned u = *(const unsigned*)(h + (size_t)i * C_DIM + c * 2);
                acc.x += bf_lo(u); acc.y += bf_hi(u);
            }
            ++i;
        }
    }
    atomicAdd(&sums[(size_t)g * C_DIM + c * 2], acc.x);
    atomicAdd(&sums[(size_t)g * C_DIM + c * 2 + 1], acc.y);
}

// ---------------- pool stage 2: mean + MLP (128->64->1) ----------------
__global__ __launch_bounds__(128) void k_mlp(
    const float* __restrict__ sums, const int* __restrict__ batch, int n,
    const float* __restrict__ Wm1, const float* __restrict__ bm1,
    const float* __restrict__ Wm2, const float* __restrict__ bm2,
    float* __restrict__ out) {
    int g = blockIdx.x;
    int t = threadIdx.x;
    int lo = 0, hi = n;
    while (lo < hi) { int m = (lo + hi) >> 1; if (batch[m] < g) lo = m + 1; else hi = m; }
    int start = lo;
    lo = start; hi = n;
    while (lo < hi) { int m = (lo + hi) >> 1; if (batch[m] < g + 1) lo = m + 1; else hi = m; }
    float cnt = (float)(lo - start);

    float mean = sums[(size_t)g * C_DIM + t] / fmaxf(cnt, 1.0f);

    __shared__ float m_s[128];
    __shared__ float hid[64];
    m_s[t] = mean;
    __syncthreads();
    if (t < 64) {
        float a = bm1[t];
#pragma unroll 4
        for (int k = 0; k < 128; ++k) a += m_s[k] * Wm1[k * 64 + t];
        hid[t] = fmaxf(a, 0.f) * Wm2[t];
    }
    __syncthreads();
    if (t < 64) {
        float v = hid[t];
        for (int off = 32; off > 0; off >>= 1) v += __shfl_down(v, off);
        if (t == 0) out[g] = v + bm2[0];
    }
}

extern "C" void kernel_launch(void* const* d_in, const int* in_sizes, int n_in,
                              void* d_out, int out_size, void* d_ws, size_t ws_size,
                              hipStream_t stream) {
    const float* x     = (const float*)d_in[0];
    const int*   eidx  = (const int*)d_in[1];
    const int*   batch = (const int*)d_in[2];
    const float* W1    = (const float*)d_in[3];
    const float* b1    = (const float*)d_in[4];
    const float* W2    = (const float*)d_in[5];
    const float* b2    = (const float*)d_in[6];
    const float* Wm1   = (const float*)d_in[7];
    const float* bm1   = (const float*)d_in[8];
    const float* Wm2   = (const float*)d_in[9];
    const float* bm2   = (const float*)d_in[10];

    const int N = in_sizes[2];       // 100000
    const int E = in_sizes[1] / 2;   // 1600000 (E % 4 == 0)
    const int G = out_size;          // 512
    const int B = (N + 127) >> BKT_SHIFT;   // 782 buckets

    char* p = (char*)d_ws;
    auto carve = [&](size_t bytes) {
        char* q = p;
        p += (bytes + 255) & ~(size_t)255;
        return q;
    };
    ushort_t* bufT   = (ushort_t*)carve((size_t)(N + 1) * C_DIM * sizeof(ushort_t)); // matmul out (+zero row)
    ushort_t* bufA   = (ushort_t*)carve((size_t)N * C_DIM * sizeof(ushort_t)); // agg out
    float*    dinv   = (float*)   carve((size_t)N * sizeof(float));
    int2*     offs2  = (int2*)    carve((size_t)N * sizeof(int2));
    int*      csr    = (int*)     carve(((size_t)E + 3 * (size_t)N + 64) * sizeof(int));
    int*      counts = (int*)     carve((size_t)CB * MAX_B * sizeof(int));  // block-major
    int*      sstart = (int*)     carve((size_t)CB * MAX_B * sizeof(int));  // block-major
    float*    gsums  = (float*)   carve((size_t)G * C_DIM * sizeof(float));
    uint4*    wf1    = (uint4*)   carve(2048 * sizeof(uint4));
    uint4*    wf2    = (uint4*)   carve(2048 * sizeof(uint4));
    int*      cursor = (int*)     carve(sizeof(int));
    // epk (packed (src<<7)|node7, 6.4 MB, block-dense) aliases bufT
    int*      epk    = (int*)bufT;

    const int* erow = eidx;
    const int* ecol = eidx + E;
    const int chunk = (ceil_div(E, CB) + 3) & ~3;   // 6252, fits CHUNK_MAX

    // --- CSR build: LDS counting sort, single edge read, dense writes ---
    k_sortchunk<<<CB + 2, 512, 0, stream>>>(erow, ecol, E, chunk, B,
                                            counts, sstart, epk,
                                            W1, W2, wf1, wf2, gsums, G * C_DIM, cursor);
    k_bfinal<<<B, 256, 0, stream>>>(epk, counts, sstart, cursor, chunk, N,
                                    offs2, dinv, csr);

    // --- conv1 ---
    k_matmul_mfma<0><<<ceil_div(N, 64), 256, 0, stream>>>(x, nullptr, wf1, dinv, bufT, N);
    k_aggregate<1><<<ceil_div(N, 8), 256, 0, stream>>>(bufT, offs2, csr, dinv, b1,
                                                       (uint4*)bufA, N);
    // --- conv2 ---
    k_matmul_mfma<1><<<ceil_div(N, 64), 256, 0, stream>>>(nullptr, bufA, wf2, dinv, bufT, N);
    k_aggregate<0><<<ceil_div(N, 8), 256, 0, stream>>>(bufT, offs2, csr, dinv, b2,
                                                       (uint4*)bufA, N);
    // --- pool (2-stage) + MLP ---
    k_pool_sum<<<ceil_div(N, POOL_CHUNK), 128, 0, stream>>>(bufA, batch, N, gsums);
    k_mlp<<<G, 128, 0, stream>>>(gsums, batch, N, Wm1, bm1, Wm2, bm2, (float*)d_out);
}